// Round 1
// baseline (387.703 us; speedup 1.0000x reference)
//
#include <hip/hip_runtime.h>

#define N_BATCH 8192
#define S 14
#define N_CELLS (N_BATCH * S * S)   // 1,605,632 cells
#define FPC 30

#define BLOCK 256
#define GRID 2048                   // grid-stride; ~3.06 cells/lane

// Direct per-lane loads: lane i owns cell i (30 floats = 15 float2 at 8B-aligned
// cell*120). Per-instruction coalescing is poor (lane stride 120B) but every
// fetched 64B line is consumed by the adjacent load of the same lane (reuse
// distance ~1 instr -> L1 hit), so HBM traffic is unchanged vs the staged
// version while removing the 15.4KB/wave LDS footprint (occupancy 10 -> ~20
// waves/CU) and the vmcnt(0)+lgkm full-drain serialization per tile.
__global__ __launch_bounds__(BLOCK, 4) void yolo_loss_kernel(
    const float* __restrict__ pred, const float* __restrict__ targ,
    float* __restrict__ out)
{
    const int tid = blockIdx.x * BLOCK + (int)threadIdx.x;
    const int stride = GRID * BLOCK;
    const float INV14 = 1.0f / 14.0f;
    const float INVN = 1.0f / (float)N_BATCH;

    float acc = 0.0f;

    for (int i = tid; i < N_CELLS; i += stride) {
        const float2* p2 = reinterpret_cast<const float2*>(pred) + (size_t)i * (FPC / 2);
        const float2* t2 = reinterpret_cast<const float2*>(targ) + (size_t)i * (FPC / 2);

        // pred floats 0..9 (boxes+conf), target floats 0..4 (box0) and 9 (conf1)
        const float2 pv0 = p2[0], pv1 = p2[1], pv2 = p2[2], pv3 = p2[3], pv4 = p2[4];
        const float2 tv0 = t2[0], tv1 = t2[1], tv2 = t2[2], tv4 = t2[4];
        // t[6],t[7] are never used by the reference -> t2[3] not loaded.

        // class floats 10..29 (both tensors), accumulate immediately to keep
        // register pressure low; compiler hoists the loads for MLP.
        float cls = 0.0f;
#pragma unroll
        for (int c = 5; c < 15; ++c) {
            const float2 a = p2[c];
            const float2 b = t2[c];
            const float dx = a.x - b.x;
            const float dy = a.y - b.y;
            cls += dx * dx + dy * dy;
        }

        const float t4 = tv2.x;
        const float objf = (t4 > 0.0f) ? 1.0f : 0.0f;
        const float noof = 1.0f - objf;

        // no-object confidence loss (conf_idx = {4, 9})
        const float d4 = pv2.x - t4;
        const float d9 = pv4.y - tv4.y;
        const float nooobj = noof * (d4 * d4 + d9 * d9);

        // target box (box 0 of target; target boxes are duplicated)
        const float tx = tv0.x * INV14, ty = tv0.y * INV14;
        const float tw = tv1.x, th = tv1.y;
        const float tx1 = tx - 0.5f * tw, ty1 = ty - 0.5f * th;
        const float tx2 = tx + 0.5f * tw, ty2 = ty + 0.5f * th;
        const float area_t = (tx2 - tx1) * (ty2 - ty1);

        float iou0, iou1;
        {   // pred box 0: p[0..3]
            const float px = pv0.x * INV14, py = pv0.y * INV14;
            const float pw = pv1.x, ph = pv1.y;
            const float px1 = px - 0.5f * pw, py1 = py - 0.5f * ph;
            const float px2 = px + 0.5f * pw, py2 = py + 0.5f * ph;
            const float ltx = fmaxf(px1, tx1), lty = fmaxf(py1, ty1);
            const float rbx = fminf(px2, tx2), rby = fminf(py2, ty2);
            const float wx = fmaxf(rbx - ltx, 0.0f);
            const float wy = fmaxf(rby - lty, 0.0f);
            const float inter = wx * wy;
            const float area_p = (px2 - px1) * (py2 - py1);
            iou0 = inter / (area_p + area_t - inter);
        }
        {   // pred box 1: p[5..8]
            const float px = pv2.y * INV14, py = pv3.x * INV14;
            const float pw = pv3.y, ph = pv4.x;
            const float px1 = px - 0.5f * pw, py1 = py - 0.5f * ph;
            const float px2 = px + 0.5f * pw, py2 = py + 0.5f * ph;
            const float ltx = fmaxf(px1, tx1), lty = fmaxf(py1, ty1);
            const float rbx = fminf(px2, tx2), rby = fminf(py2, ty2);
            const float wx = fmaxf(rbx - ltx, 0.0f);
            const float wy = fmaxf(rby - lty, 0.0f);
            const float inter = wx * wy;
            const float area_p = (px2 - px1) * (py2 - py1);
            iou1 = inter / (area_p + area_t - inter);
        }

        // responsible box: jnp.argmax -> ties pick box 0
        const bool r1 = (iou1 > iou0);
        const float max_iou = fmaxf(iou0, iou1);

        const float pc  = r1 ? pv4.y : pv2.x;   // p[5r+4]
        const float pnc = r1 ? pv2.x : pv4.y;   // p[5(1-r)+4]
        const float contain = objf * (pc - max_iou) * (pc - max_iou);
        const float not_contain = objf * pnc * pnc;

        // localization: t[5r+j] == t[j] (target boxes duplicated by concat)
        const float rx = r1 ? pv2.y : pv0.x;
        const float ry = r1 ? pv3.x : pv0.y;
        const float rw = r1 ? pv3.y : pv1.x;
        const float rh = r1 ? pv4.x : pv1.y;
        const float dx = rx - tv0.x;
        const float dy = ry - tv0.y;
        const float dw = sqrtf(rw) - sqrtf(tv1.x);
        const float dh = sqrtf(rh) - sqrtf(tv1.y);
        const float loc = objf * (dx * dx + dy * dy + dw * dw + dh * dh);

        cls *= objf;

        acc += (5.0f * loc + 2.0f * contain + 0.5f * nooobj + cls + not_contain) * INVN;
    }

    // wave reduction, then 4-wave block reduction -> one atomic per block
#pragma unroll
    for (int off = 32; off > 0; off >>= 1)
        acc += __shfl_down(acc, off, 64);

    __shared__ float wsum[BLOCK / 64];
    const int lane = threadIdx.x & 63;
    const int wid = (int)threadIdx.x >> 6;
    if (lane == 0) wsum[wid] = acc;
    __syncthreads();
    if (threadIdx.x == 0)
        atomicAdd(out, wsum[0] + wsum[1] + wsum[2] + wsum[3]);
}

extern "C" void kernel_launch(void* const* d_in, const int* in_sizes, int n_in,
                              void* d_out, int out_size, void* d_ws, size_t ws_size,
                              hipStream_t stream) {
    const float* pred = (const float*)d_in[0];
    const float* targ = (const float*)d_in[1];
    float* out = (float*)d_out;

    hipMemsetAsync(out, 0, sizeof(float), stream);

    yolo_loss_kernel<<<GRID, BLOCK, 0, stream>>>(pred, targ, out);
}